// Round 2
// baseline (2518.209 us; speedup 1.0000x reference)
//
#include <hip/hip_runtime.h>

#define INF 1e8f

constexpr int N = 2048;   // rows (x)
constexpr int M = 2048;   // cols (y)
constexpr int K = 64;     // feature dim
constexpr int W = 8;      // waves in the DP block
constexpr int T = W * 64; // 512 pipeline lanes
constexpr int C = N / T;  // 4 rows per lane
constexpr int SP = K + 4; // padded LDS stride for dist kernel

// ---------------------------------------------------------------------------
// Distance kernel, column-major output: Dt[j * N + i] = ||x_i - y_j||^2.
// (Column-major in (i,j) == row-major dist(y, x); lets each DP lane fetch its
//  4 row-values for a column as one aligned float4.)
// ---------------------------------------------------------------------------
__global__ __launch_bounds__(256) void dist_kernel(const float* __restrict__ x,
                                                   const float* __restrict__ y,
                                                   float* __restrict__ Dt) {
    __shared__ float xs[32 * SP];
    __shared__ float ys[32 * SP];
    const int t  = threadIdx.x;
    const int i0 = blockIdx.x * 32;   // x rows (fast dim of Dt -> coalesced stores)
    const int j0 = blockIdx.y * 32;   // y rows

    const float4* x4 = (const float4*)(x + (size_t)i0 * K);
    const float4* y4 = (const float4*)(y + (size_t)j0 * K);
#pragma unroll
    for (int idx = t; idx < 512; idx += 256) {
        int row = idx >> 4, c4 = idx & 15;
        *(float4*)&xs[row * SP + c4 * 4] = x4[idx];
        *(float4*)&ys[row * SP + c4 * 4] = y4[idx];
    }
    __syncthreads();

    const int jj = (t >> 4) << 1;  // y-local row
    const int ii = (t & 15) << 1;  // x-local row (fast, coalesced)
    float a00 = 0.f, a01 = 0.f, a10 = 0.f, a11 = 0.f;
#pragma unroll
    for (int k = 0; k < K; k += 2) {
        float2 xa = *(const float2*)&xs[ii * SP + k];
        float2 xb = *(const float2*)&xs[(ii + 1) * SP + k];
        float2 ya = *(const float2*)&ys[jj * SP + k];
        float2 yb = *(const float2*)&ys[(jj + 1) * SP + k];
        float d;
        d = xa.x - ya.x; a00 += d * d;  d = xa.y - ya.y; a00 += d * d;
        d = xb.x - ya.x; a01 += d * d;  d = xb.y - ya.y; a01 += d * d;
        d = xa.x - yb.x; a10 += d * d;  d = xa.y - yb.y; a10 += d * d;
        d = xb.x - yb.x; a11 += d * d;  d = xb.y - yb.y; a11 += d * d;
    }
    float* r0 = Dt + (size_t)(j0 + jj) * N + (i0 + ii);
    float* r1 = Dt + (size_t)(j0 + jj + 1) * N + (i0 + ii);
    *(float2*)r0 = make_float2(a00, a01);
    *(float2*)r1 = make_float2(a10, a11);
}

// ---------------------------------------------------------------------------
// DP: row-strip skewed register pipeline. Lane g owns rows C*g+1 .. C*g+C
// (1-indexed). At step s it processes column j = s - g + 1. All R-state in
// registers; bottom-row handoff via __shfl_up within a wave, a double-buffered
// 8-float LDS slot across wave boundaries, one barrier per step.
// ---------------------------------------------------------------------------
__device__ __forceinline__ float softmin_cell(float diag, float up, float left,
                                              float dv) {
    const float m  = fminf(fminf(diag, up), left);
    const float ss = __expf(m - diag) + __expf(m - up) + __expf(m - left);
    return dv + m - __logf(ss);
}

__global__ __launch_bounds__(T) void dp_kernel(const float* __restrict__ Dt,
                                               float* __restrict__ out) {
    __shared__ float handoff[2][W];
    const int g = threadIdx.x;   // global pipeline lane 0..T-1
    const int w = g >> 6;
    const int l = g & 63;

    if (g < 2 * W) ((float*)handoff)[g] = INF;
    __syncthreads();

    float prev[C];               // R[r, j-1] for owned rows
#pragma unroll
    for (int k = 0; k < C; ++k) prev[k] = INF;
    // top_cur/top_prev = R[rt, j] / R[rt, j-1] where rt = C*g (neighbor's
    // bottom row; row 0 boundary for lane 0: R[0,0]=0, R[0,j>=1]=INF).
    float top_cur  = (g == 0) ? 0.0f : INF;
    float top_prev = INF;
    float shfl_in  = INF;

    const float4* D4 = (const float4*)Dt;       // column j at index (j-1)*(N/4)+g
    float4 dreg = D4[g];                        // prefetch column 1

    constexpr int S = M + T - 1;                // 2559 steps
    for (int s = 0; s < S; ++s) {
        // --- shift the top-row history (value produced at end of step s-1) ---
        float incoming = shfl_in;
        if (l == 0) incoming = (w == 0) ? INF : handoff[(s + 1) & 1][w - 1];
        top_prev = top_cur;
        top_cur  = incoming;

        float bottom_new = INF;
        const int j = s - g + 1;
        if (j >= 1 && j <= M) {
            float diag = top_prev;   // R[r-1, j-1]
            float up   = top_cur;    // R[r-1, j]
#pragma unroll
            for (int k = 0; k < C; ++k) {
                const float left = prev[k];                 // R[r, j-1]
                const float dv = (k == 0) ? dreg.x : (k == 1) ? dreg.y
                               : (k == 2) ? dreg.z : dreg.w;
                const float val = softmin_cell(diag, up, left, dv);
                diag    = left;      // becomes R[(r+1)-1, j-1]
                up      = val;       // becomes R[(r+1)-1, j]
                prev[k] = val;
            }
            bottom_new = up;
            if (j < M) dreg = D4[(size_t)j * (N / 4) + g];  // prefetch col j+1
        }

        if (l == 63) handoff[s & 1][w] = bottom_new;  // cross-wave handoff
        shfl_in = __shfl_up(bottom_new, 1);           // intra-wave handoff
        __syncthreads();
    }

    if (g == T - 1) out[0] = prev[C - 1];  // R[N, M]
}

// ---------------------------------------------------------------------------
// Fallback (ws too small): fused on-the-fly distances, barrier-per-diagonal.
// ---------------------------------------------------------------------------
constexpr int L = N + 1;
__global__ __launch_bounds__(1024) void dp_fused(const float* __restrict__ x,
                                                 const float* __restrict__ y,
                                                 float* __restrict__ out) {
    __shared__ float buf[3][L];
    const int tid = threadIdx.x;
    for (int i = tid; i < L; i += 1024) {
        buf[0][i] = (i == 0) ? 0.0f : INF;
        buf[1][i] = INF;
        buf[2][i] = INF;
    }
    __syncthreads();
    for (int d = 2; d <= N + M; ++d) {
        float* curr = buf[d % 3];
        const float* p1 = buf[(d + 2) % 3];
        const float* p2 = buf[(d + 1) % 3];
        const int ilo = (d - M > 1) ? (d - M) : 1;
        const int ihi = (d - 1 < N) ? (d - 1) : N;
        for (int c = tid; c < ihi - ilo + 1; c += 1024) {
            const int i = ilo + c;
            const float* xr = x + (size_t)(i - 1) * K;
            const float* yr = y + (size_t)(d - i - 1) * K;
            float acc = 0.f;
#pragma unroll
            for (int k = 0; k < K; ++k) { float df = xr[k] - yr[k]; acc += df * df; }
            curr[i] = softmin_cell(p2[i - 1], p1[i - 1], p1[i], acc);
        }
        if (tid == 0) curr[0] = INF;
        __syncthreads();
    }
    if (tid == 0) out[0] = buf[(N + M) % 3][N];
}

// ---------------------------------------------------------------------------
extern "C" void kernel_launch(void* const* d_in, const int* in_sizes, int n_in,
                              void* d_out, int out_size, void* d_ws, size_t ws_size,
                              hipStream_t stream) {
    (void)in_sizes; (void)n_in; (void)out_size;
    const float* x = (const float*)d_in[0];
    const float* y = (const float*)d_in[1];
    float* out = (float*)d_out;
    float* Dt  = (float*)d_ws;

    const size_t need = (size_t)N * M * sizeof(float);  // 16.8 MB
    if (ws_size >= need) {
        dim3 dgrid(N / 32, M / 32);
        dist_kernel<<<dgrid, 256, 0, stream>>>(x, y, Dt);
        dp_kernel<<<1, T, 0, stream>>>(Dt, out);
    } else {
        dp_fused<<<1, 1024, 0, stream>>>(x, y, out);
    }
}

// Round 3
// 1141.783 us; speedup vs baseline: 2.2055x; 2.2055x over previous
//
#include <hip/hip_runtime.h>

#define INF 1e8f

constexpr int N = 2048;   // rows (x)
constexpr int M = 2048;   // cols (y)
constexpr int K = 64;     // feature dim
constexpr int W = 8;      // waves in the DP block
constexpr int T = W * 64; // 512 pipeline lanes
constexpr int C = N / T;  // 4 rows per lane
constexpr int KB = 16;    // steps per barrier group (cross-wave queue depth)
constexpr int PF = 4;     // D-column prefetch depth (register ring)
constexpr int SKW = 63 + KB;              // skew between consecutive waves' lane0
constexpr int S_MAX = (M - 1) + 63 + (W - 1) * SKW;  // last productive step
constexpr int NGROUPS = S_MAX / KB + 1;   // 167
constexpr int SP = K + 4;                 // padded LDS stride for dist kernel

constexpr float LOG2E = 1.44269504088896340736f;
constexpr float LN2   = 0.69314718055994530942f;

__device__ __forceinline__ float fast_exp2(float x) {
#if __has_builtin(__builtin_amdgcn_exp2f)
    return __builtin_amdgcn_exp2f(x);
#else
    return exp2f(x);
#endif
}
__device__ __forceinline__ float fast_log2(float x) {
#if __has_builtin(__builtin_amdgcn_logf)
    return __builtin_amdgcn_logf(x);
#else
    return log2f(x);
#endif
}

// softmin in the log2e-scaled domain: all R/D values carry a factor log2(e),
// so exp(m-a) == exp2(m'-a') with no multiplies on the dependent chain.
__device__ __forceinline__ float softmin_cell(float diag, float up, float left,
                                              float dv) {
    const float m = fminf(fminf(diag, up), left);
    const float s = fast_exp2(m - diag) + fast_exp2(m - up) + fast_exp2(m - left);
    return dv + m - fast_log2(s);  // s in [1,3] -> log2 arg always well-behaved
}

// ---------------------------------------------------------------------------
// Distance kernel, column-major + log2e-scaled: Dt[j*N+i] = ||x_i-y_j||^2 * log2e
// ---------------------------------------------------------------------------
__global__ __launch_bounds__(256) void dist_kernel(const float* __restrict__ x,
                                                   const float* __restrict__ y,
                                                   float* __restrict__ Dt) {
    __shared__ float xs[32 * SP];
    __shared__ float ys[32 * SP];
    const int t  = threadIdx.x;
    const int i0 = blockIdx.x * 32;   // x rows (fast dim of Dt -> coalesced)
    const int j0 = blockIdx.y * 32;   // y rows

    const float4* x4 = (const float4*)(x + (size_t)i0 * K);
    const float4* y4 = (const float4*)(y + (size_t)j0 * K);
#pragma unroll
    for (int idx = t; idx < 512; idx += 256) {
        int row = idx >> 4, c4 = idx & 15;
        *(float4*)&xs[row * SP + c4 * 4] = x4[idx];
        *(float4*)&ys[row * SP + c4 * 4] = y4[idx];
    }
    __syncthreads();

    const int jj = (t >> 4) << 1;  // y-local row
    const int ii = (t & 15) << 1;  // x-local row (fast, coalesced)
    float a00 = 0.f, a01 = 0.f, a10 = 0.f, a11 = 0.f;
#pragma unroll
    for (int k = 0; k < K; k += 2) {
        float2 xa = *(const float2*)&xs[ii * SP + k];
        float2 xb = *(const float2*)&xs[(ii + 1) * SP + k];
        float2 ya = *(const float2*)&ys[jj * SP + k];
        float2 yb = *(const float2*)&ys[(jj + 1) * SP + k];
        float d;
        d = xa.x - ya.x; a00 += d * d;  d = xa.y - ya.y; a00 += d * d;
        d = xb.x - ya.x; a01 += d * d;  d = xb.y - ya.y; a01 += d * d;
        d = xa.x - yb.x; a10 += d * d;  d = xa.y - yb.y; a10 += d * d;
        d = xb.x - yb.x; a11 += d * d;  d = xb.y - yb.y; a11 += d * d;
    }
    float* r0 = Dt + (size_t)(j0 + jj) * N + (i0 + ii);
    float* r1 = Dt + (size_t)(j0 + jj + 1) * N + (i0 + ii);
    *(float2*)r0 = make_float2(a00 * LOG2E, a01 * LOG2E);
    *(float2*)r1 = make_float2(a10 * LOG2E, a11 * LOG2E);
}

// ---------------------------------------------------------------------------
// DP: skewed register pipeline, barrier amortized over KB steps.
// Lane g = 64w + l owns rows C*g+1 .. C*g+C; at step s it processes column
// j = s - skew(g) + 1 with skew = l + w*SKW. Intra-wave handoff: __shfl_up
// every step. Cross-wave handoff: 16-deep double-buffered LDS queue, ONE
// __syncthreads per 16 steps (vmcnt/lgkm drain amortized). D prefetched
// PF=4 columns ahead in a statically-indexed register ring.
// ---------------------------------------------------------------------------
__global__ __launch_bounds__(T) void dp_kernel(const float* __restrict__ Dt,
                                               float* __restrict__ out) {
    __shared__ float queue[2][W][KB];   // 1 KiB
    const int g = threadIdx.x;
    const int w = g >> 6;
    const int l = g & 63;
    const int skew = l + w * SKW;

    for (int i = g; i < 2 * W * KB; i += T) ((float*)queue)[i] = INF;

    float prev[C];
#pragma unroll
    for (int k = 0; k < C; ++k) prev[k] = INF;
    float top_cur     = (g == 0) ? 0.0f : INF;  // R[rt, j-?]; holds R[0,0] seed
    float top_prev    = INF;
    float bottom_prev = INF;                    // this lane's bottom value, step s-1

    const float4* D4 = (const float4*)Dt;       // column j at (j-1)*(N/4)+g
    float4 ring[PF];
#pragma unroll
    for (int u = 0; u < PF; ++u) {              // prologue: columns for steps 0..PF-1
        int j  = u - skew + 1;
        int jc = min(max(j, 1), M);
        ring[u] = D4[(size_t)(jc - 1) * (N / 4) + g];
    }

    __syncthreads();

    float qv = INF;  // lanes 0..KB-1: incoming queue values for this group

    for (int grp = 0; grp < NGROUPS; ++grp) {
        // values produced during group grp-1 live in buffer (grp-1)&1
        if (w > 0 && l < KB) qv = queue[(grp & 1) ^ 1][w - 1][l];

#pragma unroll
        for (int t = 0; t < KB; ++t) {
            const int j = grp * KB + t - skew + 1;

            // ---- shift top-row history (R[rt, j-1] -> R[rt, j]) ----
            float incoming = __shfl_up(bottom_prev, 1);
            const float qq = __shfl(qv, t);          // static lane -> readlane
            if (l == 0) incoming = (w == 0) ? INF : qq;
            top_prev = top_cur;
            top_cur  = incoming;

            float bottom_new = INF;
            if (j >= 1 && j <= M) {
                const float4 dq = ring[t & (PF - 1)];
                float diag = top_prev;   // R[r-1, j-1]
                float up   = top_cur;    // R[r-1, j]
#pragma unroll
                for (int k = 0; k < C; ++k) {
                    const float left = prev[k];
                    const float dv = (k == 0) ? dq.x : (k == 1) ? dq.y
                                   : (k == 2) ? dq.z : dq.w;
                    const float val = softmin_cell(diag, up, left, dv);
                    diag    = left;
                    up      = val;
                    prev[k] = val;
                }
                bottom_new = up;
            }
            // refill ring slot for step s+PF (column j+PF), clamped, branch-free
            {
                int jc = min(max(j + PF, 1), M);
                ring[t & (PF - 1)] = D4[(size_t)(jc - 1) * (N / 4) + g];
            }

            if (l == 63) queue[grp & 1][w][t] = bottom_new;  // cross-wave queue
            bottom_prev = bottom_new;
        }
        __syncthreads();  // one barrier (and one vmcnt drain) per 16 steps
    }

    if (g == T - 1) out[0] = prev[C - 1] * LN2;  // unscale from log2e domain
}

// ---------------------------------------------------------------------------
// Fallback (ws too small): fused on-the-fly distances, barrier-per-diagonal.
// ---------------------------------------------------------------------------
constexpr int L = N + 1;
__global__ __launch_bounds__(1024) void dp_fused(const float* __restrict__ x,
                                                 const float* __restrict__ y,
                                                 float* __restrict__ out) {
    __shared__ float buf[3][L];
    const int tid = threadIdx.x;
    for (int i = tid; i < L; i += 1024) {
        buf[0][i] = (i == 0) ? 0.0f : INF;
        buf[1][i] = INF;
        buf[2][i] = INF;
    }
    __syncthreads();
    for (int d = 2; d <= N + M; ++d) {
        float* curr = buf[d % 3];
        const float* p1 = buf[(d + 2) % 3];
        const float* p2 = buf[(d + 1) % 3];
        const int ilo = (d - M > 1) ? (d - M) : 1;
        const int ihi = (d - 1 < N) ? (d - 1) : N;
        for (int c = tid; c < ihi - ilo + 1; c += 1024) {
            const int i = ilo + c;
            const float* xr = x + (size_t)(i - 1) * K;
            const float* yr = y + (size_t)(d - i - 1) * K;
            float acc = 0.f;
#pragma unroll
            for (int k = 0; k < K; ++k) { float df = xr[k] - yr[k]; acc += df * df; }
            const float m  = fminf(fminf(p2[i - 1], p1[i - 1]), p1[i]);
            const float ss = __expf(m - p2[i - 1]) + __expf(m - p1[i - 1]) +
                             __expf(m - p1[i]);
            curr[i] = acc + m - __logf(ss);
        }
        if (tid == 0) curr[0] = INF;
        __syncthreads();
    }
    if (tid == 0) out[0] = buf[(N + M) % 3][N];
}

// ---------------------------------------------------------------------------
extern "C" void kernel_launch(void* const* d_in, const int* in_sizes, int n_in,
                              void* d_out, int out_size, void* d_ws, size_t ws_size,
                              hipStream_t stream) {
    (void)in_sizes; (void)n_in; (void)out_size;
    const float* x = (const float*)d_in[0];
    const float* y = (const float*)d_in[1];
    float* out = (float*)d_out;
    float* Dt  = (float*)d_ws;

    const size_t need = (size_t)N * M * sizeof(float);  // 16.8 MB
    if (ws_size >= need) {
        dim3 dgrid(N / 32, M / 32);
        dist_kernel<<<dgrid, 256, 0, stream>>>(x, y, Dt);
        dp_kernel<<<1, T, 0, stream>>>(Dt, out);
    } else {
        dp_fused<<<1, 1024, 0, stream>>>(x, y, out);
    }
}

// Round 4
// 848.095 us; speedup vs baseline: 2.9693x; 1.3463x over previous
//
#include <hip/hip_runtime.h>

#define INF 1e8f

constexpr int N = 2048;   // rows (x)
constexpr int M = 2048;   // cols (y)
constexpr int K = 64;     // feature dim
constexpr int SP = K + 4; // padded LDS stride for dist kernels

constexpr float LOG2E = 1.44269504088896340736f;
constexpr float LN2   = 0.69314718055994530942f;

__device__ __forceinline__ float fast_exp2(float x) {
#if __has_builtin(__builtin_amdgcn_exp2f)
    return __builtin_amdgcn_exp2f(x);
#else
    return exp2f(x);
#endif
}
__device__ __forceinline__ float fast_log2(float x) {
#if __has_builtin(__builtin_amdgcn_logf)
    return __builtin_amdgcn_logf(x);
#else
    return log2f(x);
#endif
}
__device__ __forceinline__ float fmed3(float a, float b, float c) {
#if __has_builtin(__builtin_amdgcn_fmed3f)
    return __builtin_amdgcn_fmed3f(a, b, c);
#else
    return fmaxf(fminf(a, b), fminf(fmaxf(a, b), c));
#endif
}

// ===========================================================================
// PATH A: 32-CU pipelined DP, anti-diagonal-major D, global flag handoff
// ===========================================================================
constexpr int BLK   = 32;              // dp blocks (1 wave each)
constexpr int RPB   = N / BLK;         // 64 rows per block = 64 lanes, C=1
constexpr int KB2   = 32;              // steps per group / flag interval
constexpr int PF2   = 16;              // D prefetch ring depth
constexpr int NSTEP = M - 1 + 63;      // last step index = 2110
constexpr int NGRP2 = (NSTEP + KB2) / KB2;  // 66 groups (2112 steps)
constexpr int GSTR  = 2176;            // gbuf row stride (cols, padded)
constexpr int NDALLOC = 4112;          // diag rows allocated (4095 used + pad, no clamp)

// ws layout (bytes)
constexpr size_t DD_BYTES    = (size_t)NDALLOC * 2048 * 4;           // 33,685,504
constexpr size_t FLAGS_OFF   = DD_BYTES;
constexpr size_t GBUF_OFF    = FLAGS_OFF + 128;
constexpr size_t NEED_A      = GBUF_OFF + (size_t)BLK * GSTR * 4;    // ~34.0 MB

// ---------------------------------------------------------------------------
// dist2: 32x32 tile -> LDS restage -> anti-diagonal-major writeout.
// Dd[(i+j)*2048 + i] = ||x_i - y_j||^2 * log2(e)   (i,j 0-indexed)
// Per-diagonal runs are contiguous in i -> coalesced-ish stores.
// Block (0,0) also zeroes the handoff flags (dp2 runs after, stream order).
// ---------------------------------------------------------------------------
__global__ __launch_bounds__(256) void dist2(const float* __restrict__ x,
                                             const float* __restrict__ y,
                                             float* __restrict__ Dd,
                                             int* __restrict__ flags) {
    __shared__ float xs[32 * SP];
    __shared__ float ys[32 * SP];
    __shared__ float ts[32 * 34];   // +2 pad: diag reads stride 33 -> conflict-free
    const int t  = threadIdx.x;
    const int i0 = blockIdx.x * 32;
    const int j0 = blockIdx.y * 32;

    if (blockIdx.x == 0 && blockIdx.y == 0 && t < BLK) flags[t] = 0;

    const float4* x4 = (const float4*)(x + (size_t)i0 * K);
    const float4* y4 = (const float4*)(y + (size_t)j0 * K);
#pragma unroll
    for (int idx = t; idx < 512; idx += 256) {
        int row = idx >> 4, c4 = idx & 15;
        *(float4*)&xs[row * SP + c4 * 4] = x4[idx];
        *(float4*)&ys[row * SP + c4 * 4] = y4[idx];
    }
    __syncthreads();

    const int ii = (t >> 4) << 1;  // x-local row
    const int jj = (t & 15) << 1;  // y-local col
    float a00 = 0.f, a01 = 0.f, a10 = 0.f, a11 = 0.f;
#pragma unroll
    for (int k = 0; k < K; k += 2) {
        float2 xa = *(const float2*)&xs[ii * SP + k];
        float2 xb = *(const float2*)&xs[(ii + 1) * SP + k];
        float2 ya = *(const float2*)&ys[jj * SP + k];
        float2 yb = *(const float2*)&ys[(jj + 1) * SP + k];
        float d;
        d = xa.x - ya.x; a00 += d * d;  d = xa.y - ya.y; a00 += d * d;
        d = xa.x - yb.x; a01 += d * d;  d = xa.y - yb.y; a01 += d * d;
        d = xb.x - ya.x; a10 += d * d;  d = xb.y - ya.y; a10 += d * d;
        d = xb.x - yb.x; a11 += d * d;  d = xb.y - yb.y; a11 += d * d;
    }
    ts[ii * 34 + jj]           = a00;
    ts[ii * 34 + jj + 1]       = a01;
    ts[(ii + 1) * 34 + jj]     = a10;
    ts[(ii + 1) * 34 + jj + 1] = a11;
    __syncthreads();

    // 63 tile-diagonals, cells contiguous in i within each diagonal
#pragma unroll 2
    for (int idx = t; idx < 63 * 32; idx += 256) {
        const int dd  = idx >> 5;
        const int k   = idx & 31;
        const int iLo = (dd < 32) ? 0 : dd - 31;
        const int cnt = (dd < 32) ? dd + 1 : 63 - dd;
        if (k < cnt) {
            const int iL = iLo + k;
            const int jL = dd - iL;
            Dd[(size_t)(i0 + j0 + dd) * 2048 + (i0 + iL)] = ts[iL * 34 + jL] * LOG2E;
        }
    }
}

// ---------------------------------------------------------------------------
// dp2: 32 blocks x 1 wave. Lane l of block b owns row b*64+l+1 (1-indexed).
// At step s it computes column j = s - l + 1. Intra-wave handoff: __shfl_up
// (no barriers at all). Cross-block: bottom-row values -> gbuf (plain stores)
// + release-flag every 32 steps; consumer acquire-spins at group starts.
// D reads: diagonal-major, d = base + s uniform per block-step -> coalesced.
// ---------------------------------------------------------------------------
__global__ __launch_bounds__(64) void dp2(const float* __restrict__ Dd,
                                          int* __restrict__ flags,
                                          float* __restrict__ gbuf,
                                          float* __restrict__ out) {
    // XCD swizzle: runs of 4 consecutive logical blocks share an XCD
    const int b    = (blockIdx.x % 8) * 4 + blockIdx.x / 8;
    const int l    = threadIdx.x;
    const int base = b * RPB;           // 0-indexed row offset

    float prev        = INF;            // R[r, j-1]
    float top_cur     = (b == 0 && l == 0) ? 0.0f : INF;  // R[r-1, j] history
    float top_prev    = INF;
    float bottom_prev = INF;
    float qv          = INF;

    // prefetch ring: slot u holds D for step s with s%16==u
    float ring[PF2];
#pragma unroll
    for (int u = 0; u < PF2; ++u)
        ring[u] = Dd[(size_t)(base + u) * 2048 + (base + l)];

    float* gout = gbuf + (size_t)b * GSTR;          // our bottom row (b < BLK-1)
    const float* gin = gbuf + (size_t)(b - 1) * GSTR;

    for (int g = 0; g < NGRP2; ++g) {
        if (b > 0) {
            const int need = min(g * KB2 + KB2, M);
            while (__hip_atomic_load(&flags[b - 1], __ATOMIC_RELAXED,
                                     __HIP_MEMORY_SCOPE_AGENT) < need) {
                __builtin_amdgcn_s_sleep(4);
            }
            (void)__hip_atomic_load(&flags[b - 1], __ATOMIC_ACQUIRE,
                                    __HIP_MEMORY_SCOPE_AGENT);
            if (l < KB2) {
                qv = __hip_atomic_load((const float*)&gin[g * KB2 + l + 1],
                                       __ATOMIC_RELAXED, __HIP_MEMORY_SCOPE_AGENT);
            }
        }

#pragma unroll
        for (int t = 0; t < KB2; ++t) {
            const int s = g * KB2 + t;

            // shift top-row history: top_cur <- R[r-1, j]
            float incoming = __shfl_up(bottom_prev, 1);
            const float qq = __shfl(qv, t);
            if (l == 0) incoming = (b == 0) ? INF : qq;
            top_prev = top_cur;
            top_cur  = incoming;

            // softmin: S = 1 + 2^(mn-md) + 2^(mn-mx)  (2 exp2 instead of 3)
            const float dv = ring[t & (PF2 - 1)];
            const float mn = fminf(fminf(top_prev, top_cur), prev);
            const float mx = fmaxf(fmaxf(top_prev, top_cur), prev);
            const float md = fmed3(top_prev, top_cur, prev);
            const float S  = 1.0f + fast_exp2(mn - md) + fast_exp2(mn - mx);
            const float val = dv + mn - fast_log2(S);

            const bool valid = (unsigned)(s - l) < (unsigned)M;  // 1 <= j <= M
            const float bottom_new = valid ? val : INF;
            prev = valid ? val : prev;
            if (b != BLK - 1) {
                if (valid && l == 63) gout[s - 62] = bottom_new;  // j = s-63+1
            }
            bottom_prev = bottom_new;

            // refill ring slot for step s+16 (diag base+s+16); pad rows cover tail
            ring[t & (PF2 - 1)] = Dd[(size_t)(base + s + PF2) * 2048 + (base + l)];
        }

        if (b != BLK - 1 && l == 63) {
            const int jdone = (g + 1) * KB2 - 63;   // cols <= jdone fully written
            if (jdone > 0)
                __hip_atomic_store(&flags[b], jdone, __ATOMIC_RELEASE,
                                   __HIP_MEMORY_SCOPE_AGENT);
        }
    }

    if (b == BLK - 1 && l == 63) out[0] = prev * LN2;  // R[N, M], unscaled
}

// ===========================================================================
// PATH B: round-3 single-block pipeline (ws >= 16.8 MB fallback) — unchanged
// ===========================================================================
constexpr int W = 8;
constexpr int T = W * 64;
constexpr int C = N / T;
constexpr int KB = 16;
constexpr int PF = 4;
constexpr int SKW = 63 + KB;
constexpr int S_MAX = (M - 1) + 63 + (W - 1) * SKW;
constexpr int NGROUPS = S_MAX / KB + 1;

__device__ __forceinline__ float softmin_cell(float diag, float up, float left,
                                              float dv) {
    const float m = fminf(fminf(diag, up), left);
    const float s = fast_exp2(m - diag) + fast_exp2(m - up) + fast_exp2(m - left);
    return dv + m - fast_log2(s);
}

__global__ __launch_bounds__(256) void dist_kernel(const float* __restrict__ x,
                                                   const float* __restrict__ y,
                                                   float* __restrict__ Dt) {
    __shared__ float xs[32 * SP];
    __shared__ float ys[32 * SP];
    const int t  = threadIdx.x;
    const int i0 = blockIdx.x * 32;
    const int j0 = blockIdx.y * 32;

    const float4* x4 = (const float4*)(x + (size_t)i0 * K);
    const float4* y4 = (const float4*)(y + (size_t)j0 * K);
#pragma unroll
    for (int idx = t; idx < 512; idx += 256) {
        int row = idx >> 4, c4 = idx & 15;
        *(float4*)&xs[row * SP + c4 * 4] = x4[idx];
        *(float4*)&ys[row * SP + c4 * 4] = y4[idx];
    }
    __syncthreads();

    const int jj = (t >> 4) << 1;
    const int ii = (t & 15) << 1;
    float a00 = 0.f, a01 = 0.f, a10 = 0.f, a11 = 0.f;
#pragma unroll
    for (int k = 0; k < K; k += 2) {
        float2 xa = *(const float2*)&xs[ii * SP + k];
        float2 xb = *(const float2*)&xs[(ii + 1) * SP + k];
        float2 ya = *(const float2*)&ys[jj * SP + k];
        float2 yb = *(const float2*)&ys[(jj + 1) * SP + k];
        float d;
        d = xa.x - ya.x; a00 += d * d;  d = xa.y - ya.y; a00 += d * d;
        d = xb.x - ya.x; a01 += d * d;  d = xb.y - ya.y; a01 += d * d;
        d = xa.x - yb.x; a10 += d * d;  d = xa.y - yb.y; a10 += d * d;
        d = xb.x - yb.x; a11 += d * d;  d = xb.y - yb.y; a11 += d * d;
    }
    float* r0 = Dt + (size_t)(j0 + jj) * N + (i0 + ii);
    float* r1 = Dt + (size_t)(j0 + jj + 1) * N + (i0 + ii);
    *(float2*)r0 = make_float2(a00 * LOG2E, a01 * LOG2E);
    *(float2*)r1 = make_float2(a10 * LOG2E, a11 * LOG2E);
}

__global__ __launch_bounds__(T) void dp_kernel(const float* __restrict__ Dt,
                                               float* __restrict__ out) {
    __shared__ float queue[2][W][KB];
    const int g = threadIdx.x;
    const int w = g >> 6;
    const int l = g & 63;
    const int skew = l + w * SKW;

    for (int i = g; i < 2 * W * KB; i += T) ((float*)queue)[i] = INF;

    float prev[C];
#pragma unroll
    for (int k = 0; k < C; ++k) prev[k] = INF;
    float top_cur     = (g == 0) ? 0.0f : INF;
    float top_prev    = INF;
    float bottom_prev = INF;

    const float4* D4 = (const float4*)Dt;
    float4 ring[PF];
#pragma unroll
    for (int u = 0; u < PF; ++u) {
        int j  = u - skew + 1;
        int jc = min(max(j, 1), M);
        ring[u] = D4[(size_t)(jc - 1) * (N / 4) + g];
    }

    __syncthreads();

    float qv = INF;

    for (int grp = 0; grp < NGROUPS; ++grp) {
        if (w > 0 && l < KB) qv = queue[(grp & 1) ^ 1][w - 1][l];

#pragma unroll
        for (int t = 0; t < KB; ++t) {
            const int j = grp * KB + t - skew + 1;

            float incoming = __shfl_up(bottom_prev, 1);
            const float qq = __shfl(qv, t);
            if (l == 0) incoming = (w == 0) ? INF : qq;
            top_prev = top_cur;
            top_cur  = incoming;

            float bottom_new = INF;
            if (j >= 1 && j <= M) {
                const float4 dq = ring[t & (PF - 1)];
                float diag = top_prev;
                float up   = top_cur;
#pragma unroll
                for (int k = 0; k < C; ++k) {
                    const float left = prev[k];
                    const float dv = (k == 0) ? dq.x : (k == 1) ? dq.y
                                   : (k == 2) ? dq.z : dq.w;
                    const float val = softmin_cell(diag, up, left, dv);
                    diag    = left;
                    up      = val;
                    prev[k] = val;
                }
                bottom_new = up;
            }
            {
                int jc = min(max(j + PF, 1), M);
                ring[t & (PF - 1)] = D4[(size_t)(jc - 1) * (N / 4) + g];
            }

            if (l == 63) queue[grp & 1][w][t] = bottom_new;
            bottom_prev = bottom_new;
        }
        __syncthreads();
    }

    if (g == T - 1) out[0] = prev[C - 1] * LN2;
}

// ===========================================================================
// PATH C: fused fallback (tiny ws)
// ===========================================================================
constexpr int L = N + 1;
__global__ __launch_bounds__(1024) void dp_fused(const float* __restrict__ x,
                                                 const float* __restrict__ y,
                                                 float* __restrict__ out) {
    __shared__ float buf[3][L];
    const int tid = threadIdx.x;
    for (int i = tid; i < L; i += 1024) {
        buf[0][i] = (i == 0) ? 0.0f : INF;
        buf[1][i] = INF;
        buf[2][i] = INF;
    }
    __syncthreads();
    for (int d = 2; d <= N + M; ++d) {
        float* curr = buf[d % 3];
        const float* p1 = buf[(d + 2) % 3];
        const float* p2 = buf[(d + 1) % 3];
        const int ilo = (d - M > 1) ? (d - M) : 1;
        const int ihi = (d - 1 < N) ? (d - 1) : N;
        for (int c = tid; c < ihi - ilo + 1; c += 1024) {
            const int i = ilo + c;
            const float* xr = x + (size_t)(i - 1) * K;
            const float* yr = y + (size_t)(d - i - 1) * K;
            float acc = 0.f;
#pragma unroll
            for (int k = 0; k < K; ++k) { float df = xr[k] - yr[k]; acc += df * df; }
            const float m  = fminf(fminf(p2[i - 1], p1[i - 1]), p1[i]);
            const float ss = __expf(m - p2[i - 1]) + __expf(m - p1[i - 1]) +
                             __expf(m - p1[i]);
            curr[i] = acc + m - __logf(ss);
        }
        if (tid == 0) curr[0] = INF;
        __syncthreads();
    }
    if (tid == 0) out[0] = buf[(N + M) % 3][N];
}

// ===========================================================================
extern "C" void kernel_launch(void* const* d_in, const int* in_sizes, int n_in,
                              void* d_out, int out_size, void* d_ws, size_t ws_size,
                              hipStream_t stream) {
    (void)in_sizes; (void)n_in; (void)out_size;
    const float* x = (const float*)d_in[0];
    const float* y = (const float*)d_in[1];
    float* out = (float*)d_out;

    if (ws_size >= NEED_A) {
        float* Dd    = (float*)d_ws;
        int*   flags = (int*)((char*)d_ws + FLAGS_OFF);
        float* gbuf  = (float*)((char*)d_ws + GBUF_OFF);
        dim3 dg(64, 64);
        dist2<<<dg, 256, 0, stream>>>(x, y, Dd, flags);
        dp2<<<BLK, 64, 0, stream>>>(Dd, flags, gbuf, out);
    } else if (ws_size >= (size_t)N * M * sizeof(float)) {
        float* Dt = (float*)d_ws;
        dim3 dg(N / 32, M / 32);
        dist_kernel<<<dg, 256, 0, stream>>>(x, y, Dt);
        dp_kernel<<<1, T, 0, stream>>>(Dt, out);
    } else {
        dp_fused<<<1, 1024, 0, stream>>>(x, y, out);
    }
}

// Round 5
// 667.094 us; speedup vs baseline: 3.7749x; 1.2713x over previous
//
#include <hip/hip_runtime.h>

#define INF 1e8f

constexpr int N = 2048;   // rows (x)
constexpr int M = 2048;   // cols (y)
constexpr int K = 64;     // feature dim
constexpr int SP = K + 4; // padded LDS stride for dist kernels

constexpr float LOG2E = 1.44269504088896340736f;
constexpr float LN2   = 0.69314718055994530942f;

__device__ __forceinline__ float fast_exp2(float x) {
#if __has_builtin(__builtin_amdgcn_exp2f)
    return __builtin_amdgcn_exp2f(x);
#else
    return exp2f(x);
#endif
}
__device__ __forceinline__ float fast_log2(float x) {
#if __has_builtin(__builtin_amdgcn_logf)
    return __builtin_amdgcn_logf(x);
#else
    return log2f(x);
#endif
}
__device__ __forceinline__ float fmed3(float a, float b, float c) {
#if __has_builtin(__builtin_amdgcn_fmed3f)
    return __builtin_amdgcn_fmed3f(a, b, c);
#else
    return fmaxf(fminf(a, b), fminf(fmaxf(a, b), c));
#endif
}

// --- DPP cross-lane shift (VALU pipe, ~4cy; replaces ds_permute ~120cy) ---
constexpr int DPP_WAVE_SHR1 = 0x138;  // dest[i] = src[i-1]; lane0 -> old
constexpr int DPP_WAVE_SHL1 = 0x130;  // dest[i] = src[i+1]; lane63 -> old

template <int CTRL>
__device__ __forceinline__ float dpp_mov(float oldv, float src) {
#if __has_builtin(__builtin_amdgcn_update_dpp)
    return __int_as_float(__builtin_amdgcn_update_dpp(
        __float_as_int(oldv), __float_as_int(src), CTRL, 0xF, 0xF, false));
#else
    if (CTRL == DPP_WAVE_SHR1) {
        float v = __shfl_up(src, 1);
        return (__lane_id() == 0) ? oldv : v;
    } else {
        float v = __shfl_down(src, 1);
        return (__lane_id() == 63) ? oldv : v;
    }
#endif
}

// ===========================================================================
// PATH A: 32-CU pipelined DP, anti-diagonal-major D, global flag handoff
// ===========================================================================
constexpr int BLK   = 32;              // dp blocks (1 wave each)
constexpr int RPB   = N / BLK;         // 64 rows per block
constexpr int KB2   = 32;              // steps per group / flag interval
constexpr int PF2   = 32;              // D prefetch ring depth (1 group)
constexpr int NGRP2 = 66;              // steps 0..2111
constexpr int GSTR  = 2176;            // gbuf row stride (floats)
constexpr int NDALLOC = 4128;          // diag rows allocated (max touched 4127)

constexpr size_t DD_BYTES  = (size_t)NDALLOC * 2048 * 4;
constexpr size_t FLAGS_OFF = DD_BYTES;
constexpr size_t GBUF_OFF  = FLAGS_OFF + 128;
constexpr size_t NEED_A    = GBUF_OFF + (size_t)BLK * GSTR * 4;

// ---------------------------------------------------------------------------
// dist2: 32x32 tile -> LDS restage -> anti-diagonal-major writeout.
// Dd[(i+j)*2048 + i] = ||x_i - y_j||^2 * log2(e)
// ---------------------------------------------------------------------------
__global__ __launch_bounds__(256) void dist2(const float* __restrict__ x,
                                             const float* __restrict__ y,
                                             float* __restrict__ Dd,
                                             int* __restrict__ flags) {
    __shared__ float xs[32 * SP];
    __shared__ float ys[32 * SP];
    __shared__ float ts[32 * 34];
    const int t  = threadIdx.x;
    const int i0 = blockIdx.x * 32;
    const int j0 = blockIdx.y * 32;

    if (blockIdx.x == 0 && blockIdx.y == 0 && t < BLK) flags[t] = 0;

    const float4* x4 = (const float4*)(x + (size_t)i0 * K);
    const float4* y4 = (const float4*)(y + (size_t)j0 * K);
#pragma unroll
    for (int idx = t; idx < 512; idx += 256) {
        int row = idx >> 4, c4 = idx & 15;
        *(float4*)&xs[row * SP + c4 * 4] = x4[idx];
        *(float4*)&ys[row * SP + c4 * 4] = y4[idx];
    }
    __syncthreads();

    const int ii = (t >> 4) << 1;  // x-local row
    const int jj = (t & 15) << 1;  // y-local col
    float a00 = 0.f, a01 = 0.f, a10 = 0.f, a11 = 0.f;
#pragma unroll
    for (int k = 0; k < K; k += 2) {
        float2 xa = *(const float2*)&xs[ii * SP + k];
        float2 xb = *(const float2*)&xs[(ii + 1) * SP + k];
        float2 ya = *(const float2*)&ys[jj * SP + k];
        float2 yb = *(const float2*)&ys[(jj + 1) * SP + k];
        float d;
        d = xa.x - ya.x; a00 += d * d;  d = xa.y - ya.y; a00 += d * d;
        d = xa.x - yb.x; a01 += d * d;  d = xa.y - yb.y; a01 += d * d;
        d = xb.x - ya.x; a10 += d * d;  d = xb.y - ya.y; a10 += d * d;
        d = xb.x - yb.x; a11 += d * d;  d = xb.y - yb.y; a11 += d * d;
    }
    // float2 stores: each wave's 64 lanes span all 32 banks 2-way (free)
    *(float2*)&ts[ii * 34 + jj]       = make_float2(a00, a01);
    *(float2*)&ts[(ii + 1) * 34 + jj] = make_float2(a10, a11);
    __syncthreads();

#pragma unroll 2
    for (int idx = t; idx < 63 * 32; idx += 256) {
        const int dd  = idx >> 5;
        const int k   = idx & 31;
        const int iLo = (dd < 32) ? 0 : dd - 31;
        const int cnt = (dd < 32) ? dd + 1 : 63 - dd;
        if (k < cnt) {
            const int iL = iLo + k;
            const int jL = dd - iL;
            Dd[(size_t)(i0 + j0 + dd) * 2048 + (i0 + iL)] = ts[iL * 34 + jL] * LOG2E;
        }
    }
}

// ---------------------------------------------------------------------------
// dp2 group body. Interior groups (g in [2,64)): no masking at all.
// ---------------------------------------------------------------------------
template <bool EDGE>
__device__ __forceinline__ void dp_group(const int sbase, const int l,
                                         const bool store_row,
                                         float& prev, float& top_cur,
                                         float& bottom_prev, float& qv,
                                         float (&ring)[PF2],
                                         const float* __restrict__ dnext,
                                         float* __restrict__ gout) {
#pragma unroll
    for (int t = 0; t < KB2; ++t) {
        const int s = sbase + t;
        // incoming = (lane0) ? qv[lane0] : bottom_prev[lane-1]  — one DPP op
        const float incoming = dpp_mov<DPP_WAVE_SHR1>(qv, bottom_prev);
        const float tp = top_cur;   // R[r-1, j-1]
        top_cur = incoming;         // R[r-1, j]

        const float dv = ring[t];
        const float mn = fminf(fminf(tp, top_cur), prev);
        const float mx = fmaxf(fmaxf(tp, top_cur), prev);
        const float md = fmed3(tp, top_cur, prev);
        const float S  = 1.0f + fast_exp2(mn - md) + fast_exp2(mn - mx);
        const float val = dv + mn - fast_log2(S);

        if constexpr (EDGE) {
            const bool valid = (unsigned)(s - l) < 2048u;
            const float bn = valid ? val : INF;
            prev = valid ? val : prev;
            if (store_row && valid && l == 63) gout[s - 62] = bn;
            bottom_prev = bn;
        } else {
            prev = val;
            if (store_row && l == 63) gout[s - 62] = val;
            bottom_prev = val;
        }

        qv = dpp_mov<DPP_WAVE_SHL1>(qv, qv);   // rotate handoff feed
        ring[t] = dnext[(size_t)t * 2048];     // refill for step s+32
    }
}

// ---------------------------------------------------------------------------
// dp2: 32 blocks x 1 wave, lane l of block b owns row b*64+l+1.
// Cross-block handoff: gbuf + release/acquire flags, prefetched one group
// ahead (non-blocking check) so group-start latency hides under compute.
// ---------------------------------------------------------------------------
__global__ __launch_bounds__(64) void dp2(const float* __restrict__ Dd,
                                          int* __restrict__ flags,
                                          float* __restrict__ gbuf,
                                          float* __restrict__ out) {
    const int b    = (blockIdx.x % 8) * 4 + blockIdx.x / 8;  // XCD swizzle
    const int l    = threadIdx.x;
    const int base = b * RPB;
    const bool store_row = (b != BLK - 1);

    float prev        = INF;
    float top_cur     = (b == 0 && l == 0) ? 0.0f : INF;
    float bottom_prev = INF;
    float qv = INF, qv_next = INF;
    bool have_next = false;

    float ring[PF2];
#pragma unroll
    for (int u = 0; u < PF2; ++u)
        ring[u] = Dd[(size_t)(base + u) * 2048 + (base + l)];

    float* gout = gbuf + (size_t)b * GSTR;
    const float* gin = gbuf + (size_t)(b - 1) * GSTR;
    const int* flagp = flags + (b > 0 ? b - 1 : 0);
    const float* dnext = Dd + (size_t)(base + KB2) * 2048 + (base + l);

    for (int g = 0; g < NGRP2; ++g) {
        if (b > 0 && g < 64) {   // lane0's cells are invalid for g >= 64
            if (have_next) {
                qv = qv_next;
                have_next = false;
            } else {
                const int need = 32 * g + 32;   // <= 2048 for g <= 63
                while (__hip_atomic_load(flagp, __ATOMIC_RELAXED,
                                         __HIP_MEMORY_SCOPE_AGENT) < need)
                    __builtin_amdgcn_s_sleep(1);
                (void)__hip_atomic_load(flagp, __ATOMIC_ACQUIRE,
                                        __HIP_MEMORY_SCOPE_AGENT);
                if (l < KB2)
                    qv = __hip_atomic_load(&gin[32 * g + l + 1],
                                           __ATOMIC_RELAXED,
                                           __HIP_MEMORY_SCOPE_AGENT);
            }
            // non-blocking prefetch of next group's handoff row
            const int g1 = g + 1;
            if (g1 < 64) {
                if (__hip_atomic_load(flagp, __ATOMIC_RELAXED,
                                      __HIP_MEMORY_SCOPE_AGENT) >= 32 * g1 + 32) {
                    (void)__hip_atomic_load(flagp, __ATOMIC_ACQUIRE,
                                            __HIP_MEMORY_SCOPE_AGENT);
                    if (l < KB2)
                        qv_next = __hip_atomic_load(&gin[32 * g1 + l + 1],
                                                    __ATOMIC_RELAXED,
                                                    __HIP_MEMORY_SCOPE_AGENT);
                    have_next = true;
                }
            }
        }

        const int sbase = g * KB2;
        if ((g < 2) | (g >= 64))
            dp_group<true >(sbase, l, store_row, prev, top_cur, bottom_prev,
                            qv, ring, dnext, gout);
        else
            dp_group<false>(sbase, l, store_row, prev, top_cur, bottom_prev,
                            qv, ring, dnext, gout);
        dnext += (size_t)KB2 * 2048;

        if (store_row && l == 63) {
            int jd = 32 * g - 31;           // cols <= jd fully written
            if (jd > 0) {
                if (jd > 2048) jd = 2048;
                __hip_atomic_store(&flags[b], jd, __ATOMIC_RELEASE,
                                   __HIP_MEMORY_SCOPE_AGENT);
            }
        }
    }

    if (b == BLK - 1 && l == 63) out[0] = prev * LN2;  // R[N, M]
}

// ===========================================================================
// PATH B: single-block pipeline fallback (ws >= 16.8 MB) — unchanged
// ===========================================================================
constexpr int W = 8;
constexpr int T = W * 64;
constexpr int C = N / T;
constexpr int KB = 16;
constexpr int PF = 4;
constexpr int SKW = 63 + KB;
constexpr int S_MAX = (M - 1) + 63 + (W - 1) * SKW;
constexpr int NGROUPS = S_MAX / KB + 1;

__device__ __forceinline__ float softmin_cell(float diag, float up, float left,
                                              float dv) {
    const float m = fminf(fminf(diag, up), left);
    const float s = fast_exp2(m - diag) + fast_exp2(m - up) + fast_exp2(m - left);
    return dv + m - fast_log2(s);
}

__global__ __launch_bounds__(256) void dist_kernel(const float* __restrict__ x,
                                                   const float* __restrict__ y,
                                                   float* __restrict__ Dt) {
    __shared__ float xs[32 * SP];
    __shared__ float ys[32 * SP];
    const int t  = threadIdx.x;
    const int i0 = blockIdx.x * 32;
    const int j0 = blockIdx.y * 32;

    const float4* x4 = (const float4*)(x + (size_t)i0 * K);
    const float4* y4 = (const float4*)(y + (size_t)j0 * K);
#pragma unroll
    for (int idx = t; idx < 512; idx += 256) {
        int row = idx >> 4, c4 = idx & 15;
        *(float4*)&xs[row * SP + c4 * 4] = x4[idx];
        *(float4*)&ys[row * SP + c4 * 4] = y4[idx];
    }
    __syncthreads();

    const int jj = (t >> 4) << 1;
    const int ii = (t & 15) << 1;
    float a00 = 0.f, a01 = 0.f, a10 = 0.f, a11 = 0.f;
#pragma unroll
    for (int k = 0; k < K; k += 2) {
        float2 xa = *(const float2*)&xs[ii * SP + k];
        float2 xb = *(const float2*)&xs[(ii + 1) * SP + k];
        float2 ya = *(const float2*)&ys[jj * SP + k];
        float2 yb = *(const float2*)&ys[(jj + 1) * SP + k];
        float d;
        d = xa.x - ya.x; a00 += d * d;  d = xa.y - ya.y; a00 += d * d;
        d = xb.x - ya.x; a01 += d * d;  d = xb.y - ya.y; a01 += d * d;
        d = xa.x - yb.x; a10 += d * d;  d = xa.y - yb.y; a10 += d * d;
        d = xb.x - yb.x; a11 += d * d;  d = xb.y - yb.y; a11 += d * d;
    }
    float* r0 = Dt + (size_t)(j0 + jj) * N + (i0 + ii);
    float* r1 = Dt + (size_t)(j0 + jj + 1) * N + (i0 + ii);
    *(float2*)r0 = make_float2(a00 * LOG2E, a01 * LOG2E);
    *(float2*)r1 = make_float2(a10 * LOG2E, a11 * LOG2E);
}

__global__ __launch_bounds__(T) void dp_kernel(const float* __restrict__ Dt,
                                               float* __restrict__ out) {
    __shared__ float queue[2][W][KB];
    const int g = threadIdx.x;
    const int w = g >> 6;
    const int l = g & 63;
    const int skew = l + w * SKW;

    for (int i = g; i < 2 * W * KB; i += T) ((float*)queue)[i] = INF;

    float prev[C];
#pragma unroll
    for (int k = 0; k < C; ++k) prev[k] = INF;
    float top_cur     = (g == 0) ? 0.0f : INF;
    float top_prev    = INF;
    float bottom_prev = INF;

    const float4* D4 = (const float4*)Dt;
    float4 ring[PF];
#pragma unroll
    for (int u = 0; u < PF; ++u) {
        int j  = u - skew + 1;
        int jc = min(max(j, 1), M);
        ring[u] = D4[(size_t)(jc - 1) * (N / 4) + g];
    }

    __syncthreads();

    float qv = INF;

    for (int grp = 0; grp < NGROUPS; ++grp) {
        if (w > 0 && l < KB) qv = queue[(grp & 1) ^ 1][w - 1][l];

#pragma unroll
        for (int t = 0; t < KB; ++t) {
            const int j = grp * KB + t - skew + 1;

            float incoming = __shfl_up(bottom_prev, 1);
            const float qq = __shfl(qv, t);
            if (l == 0) incoming = (w == 0) ? INF : qq;
            top_prev = top_cur;
            top_cur  = incoming;

            float bottom_new = INF;
            if (j >= 1 && j <= M) {
                const float4 dq = ring[t & (PF - 1)];
                float diag = top_prev;
                float up   = top_cur;
#pragma unroll
                for (int k = 0; k < C; ++k) {
                    const float left = prev[k];
                    const float dv = (k == 0) ? dq.x : (k == 1) ? dq.y
                                   : (k == 2) ? dq.z : dq.w;
                    const float val = softmin_cell(diag, up, left, dv);
                    diag    = left;
                    up      = val;
                    prev[k] = val;
                }
                bottom_new = up;
            }
            {
                int jc = min(max(j + PF, 1), M);
                ring[t & (PF - 1)] = D4[(size_t)(jc - 1) * (N / 4) + g];
            }

            if (l == 63) queue[grp & 1][w][t] = bottom_new;
            bottom_prev = bottom_new;
        }
        __syncthreads();
    }

    if (g == T - 1) out[0] = prev[C - 1] * LN2;
}

// ===========================================================================
// PATH C: fused fallback (tiny ws)
// ===========================================================================
constexpr int L = N + 1;
__global__ __launch_bounds__(1024) void dp_fused(const float* __restrict__ x,
                                                 const float* __restrict__ y,
                                                 float* __restrict__ out) {
    __shared__ float buf[3][L];
    const int tid = threadIdx.x;
    for (int i = tid; i < L; i += 1024) {
        buf[0][i] = (i == 0) ? 0.0f : INF;
        buf[1][i] = INF;
        buf[2][i] = INF;
    }
    __syncthreads();
    for (int d = 2; d <= N + M; ++d) {
        float* curr = buf[d % 3];
        const float* p1 = buf[(d + 2) % 3];
        const float* p2 = buf[(d + 1) % 3];
        const int ilo = (d - M > 1) ? (d - M) : 1;
        const int ihi = (d - 1 < N) ? (d - 1) : N;
        for (int c = tid; c < ihi - ilo + 1; c += 1024) {
            const int i = ilo + c;
            const float* xr = x + (size_t)(i - 1) * K;
            const float* yr = y + (size_t)(d - i - 1) * K;
            float acc = 0.f;
#pragma unroll
            for (int k = 0; k < K; ++k) { float df = xr[k] - yr[k]; acc += df * df; }
            const float m  = fminf(fminf(p2[i - 1], p1[i - 1]), p1[i]);
            const float ss = __expf(m - p2[i - 1]) + __expf(m - p1[i - 1]) +
                             __expf(m - p1[i]);
            curr[i] = acc + m - __logf(ss);
        }
        if (tid == 0) curr[0] = INF;
        __syncthreads();
    }
    if (tid == 0) out[0] = buf[(N + M) % 3][N];
}

// ===========================================================================
extern "C" void kernel_launch(void* const* d_in, const int* in_sizes, int n_in,
                              void* d_out, int out_size, void* d_ws, size_t ws_size,
                              hipStream_t stream) {
    (void)in_sizes; (void)n_in; (void)out_size;
    const float* x = (const float*)d_in[0];
    const float* y = (const float*)d_in[1];
    float* out = (float*)d_out;

    if (ws_size >= NEED_A) {
        float* Dd    = (float*)d_ws;
        int*   flags = (int*)((char*)d_ws + FLAGS_OFF);
        float* gbuf  = (float*)((char*)d_ws + GBUF_OFF);
        dim3 dg(64, 64);
        dist2<<<dg, 256, 0, stream>>>(x, y, Dd, flags);
        dp2<<<BLK, 64, 0, stream>>>(Dd, flags, gbuf, out);
    } else if (ws_size >= (size_t)N * M * sizeof(float)) {
        float* Dt = (float*)d_ws;
        dim3 dg(N / 32, M / 32);
        dist_kernel<<<dg, 256, 0, stream>>>(x, y, Dt);
        dp_kernel<<<1, T, 0, stream>>>(Dt, out);
    } else {
        dp_fused<<<1, 1024, 0, stream>>>(x, y, out);
    }
}

// Round 6
// 472.132 us; speedup vs baseline: 5.3337x; 1.4129x over previous
//
#include <hip/hip_runtime.h>

#define INF 1e8f

constexpr int N = 2048;   // rows (x)
constexpr int M = 2048;   // cols (y)
constexpr int K = 64;     // feature dim
constexpr int SP = K + 4; // padded LDS stride for dist kernels

constexpr float LOG2E = 1.44269504088896340736f;
constexpr float LN2   = 0.69314718055994530942f;

__device__ __forceinline__ float fast_exp2(float x) {
#if __has_builtin(__builtin_amdgcn_exp2f)
    return __builtin_amdgcn_exp2f(x);
#else
    return exp2f(x);
#endif
}
__device__ __forceinline__ float fast_log2(float x) {
#if __has_builtin(__builtin_amdgcn_logf)
    return __builtin_amdgcn_logf(x);
#else
    return log2f(x);
#endif
}
__device__ __forceinline__ float fmed3(float a, float b, float c) {
#if __has_builtin(__builtin_amdgcn_fmed3f)
    return __builtin_amdgcn_fmed3f(a, b, c);
#else
    return fmaxf(fminf(a, b), fminf(fmaxf(a, b), c));
#endif
}
__device__ __forceinline__ void sched_fence() {
#if __has_builtin(__builtin_amdgcn_sched_barrier)
    __builtin_amdgcn_sched_barrier(0);
#endif
}

// --- DPP cross-lane shift (VALU pipe) ---
constexpr int DPP_WAVE_SHR1 = 0x138;  // dest[i] = src[i-1]; lane0 -> old
constexpr int DPP_WAVE_SHL1 = 0x130;  // dest[i] = src[i+1]; lane63 -> old

template <int CTRL>
__device__ __forceinline__ float dpp_mov(float oldv, float src) {
#if __has_builtin(__builtin_amdgcn_update_dpp)
    return __int_as_float(__builtin_amdgcn_update_dpp(
        __float_as_int(oldv), __float_as_int(src), CTRL, 0xF, 0xF, false));
#else
    if (CTRL == DPP_WAVE_SHR1) {
        float v = __shfl_up(src, 1);
        return (__lane_id() == 0) ? oldv : v;
    } else {
        float v = __shfl_down(src, 1);
        return (__lane_id() == 63) ? oldv : v;
    }
#endif
}

// ===========================================================================
// PATH A: 32-CU pipelined DP.
// D layout: Dg[b][g][l][t]  (flat ((b*NGA+g)*2048 + l*32 + t), value =
//   ||x_{b*64+l} - y_{c}||^2 * log2e  with  c = 32g + t - l   (0-indexed col)
// Each lane's 32 per-group values are 128B contiguous -> 8 dwordx4 loads,
// double-buffered in registers. Steady-state step body: NO vector-mem ops.
// ===========================================================================
constexpr int BLK   = 32;
constexpr int RPB   = N / BLK;         // 64 rows per block
constexpr int KB2   = 32;              // steps per group
constexpr int NGRP2 = 66;              // steps 0..2111
constexpr int NGA   = NGRP2;
constexpr int GSTR  = 2176;            // gbuf row stride (floats)

constexpr size_t DG_BYTES  = (size_t)BLK * NGA * 2048 * 4;   // 17,301,504
constexpr size_t FLAGS_OFF = DG_BYTES;
constexpr size_t GBUF_OFF  = FLAGS_OFF + 128;
constexpr size_t NEED_A    = GBUF_OFF + (size_t)BLK * GSTR * 4;

// ---------------------------------------------------------------------------
// dist2: 32x32 tile -> LDS restage -> [b][g][l][t] writeout (runs of 32
// consecutive s per row -> near-contiguous stores).
// ---------------------------------------------------------------------------
__global__ __launch_bounds__(256) void dist2(const float* __restrict__ x,
                                             const float* __restrict__ y,
                                             float* __restrict__ Dg,
                                             int* __restrict__ flags) {
    __shared__ float xs[32 * SP];
    __shared__ float ys[32 * SP];
    __shared__ float ts[32 * 34];
    const int t  = threadIdx.x;
    const int i0 = blockIdx.x * 32;
    const int j0 = blockIdx.y * 32;

    if (blockIdx.x == 0 && blockIdx.y == 0 && t < BLK) flags[t] = 0;

    const float4* x4 = (const float4*)(x + (size_t)i0 * K);
    const float4* y4 = (const float4*)(y + (size_t)j0 * K);
#pragma unroll
    for (int idx = t; idx < 512; idx += 256) {
        int row = idx >> 4, c4 = idx & 15;
        *(float4*)&xs[row * SP + c4 * 4] = x4[idx];
        *(float4*)&ys[row * SP + c4 * 4] = y4[idx];
    }
    __syncthreads();

    const int ii = (t >> 4) << 1;  // x-local row
    const int jj = (t & 15) << 1;  // y-local col
    float a00 = 0.f, a01 = 0.f, a10 = 0.f, a11 = 0.f;
#pragma unroll
    for (int k = 0; k < K; k += 2) {
        float2 xa = *(const float2*)&xs[ii * SP + k];
        float2 xb = *(const float2*)&xs[(ii + 1) * SP + k];
        float2 ya = *(const float2*)&ys[jj * SP + k];
        float2 yb = *(const float2*)&ys[(jj + 1) * SP + k];
        float d;
        d = xa.x - ya.x; a00 += d * d;  d = xa.y - ya.y; a00 += d * d;
        d = xa.x - yb.x; a01 += d * d;  d = xa.y - yb.y; a01 += d * d;
        d = xb.x - ya.x; a10 += d * d;  d = xb.y - ya.y; a10 += d * d;
        d = xb.x - yb.x; a11 += d * d;  d = xb.y - yb.y; a11 += d * d;
    }
    *(float2*)&ts[ii * 34 + jj]       = make_float2(a00, a01);
    *(float2*)&ts[(ii + 1) * 34 + jj] = make_float2(a10, a11);
    __syncthreads();

#pragma unroll
    for (int it = 0; it < 4; ++it) {
        const int idx = t + it * 256;          // 0..1023
        const int iL  = idx >> 5, jL = idx & 31;
        const int gi  = i0 + iL;               // global row
        const int gc  = j0 + jL;               // global col
        const int bb  = gi >> 6, ll = gi & 63;
        const int s   = gc + ll;               // step index for this cell
        Dg[(size_t)(bb * NGA + (s >> 5)) * 2048 + (ll << 5) + (s & 31)] =
            ts[iL * 34 + jL] * LOG2E;
    }
}

// ---------------------------------------------------------------------------
// dp2 group body: 32 steps, pure VALU + one exec-masked ds_write per step.
// rd[] is the statically-indexed register buffer for THIS group.
// ---------------------------------------------------------------------------
template <bool EDGE>
__device__ __forceinline__ void dp_body(const int sbase, const int l,
                                        float& prev, float& top_cur,
                                        float& bottom_prev, float& qv,
                                        const float4 (&rd)[8],
                                        float* __restrict__ bot) {
#pragma unroll
    for (int t = 0; t < KB2; ++t) {
        // incoming = (lane0) ? qv[lane0] : bottom_prev[lane-1]
        const float incoming = dpp_mov<DPP_WAVE_SHR1>(qv, bottom_prev);
        const float tp = top_cur;   // R[r-1, j-1]
        top_cur = incoming;         // R[r-1, j]

        const float4 q4 = rd[t >> 2];
        const float dv = ((t & 3) == 0) ? q4.x : ((t & 3) == 1) ? q4.y
                       : ((t & 3) == 2) ? q4.z : q4.w;
        const float mn = fminf(fminf(tp, top_cur), prev);
        const float mx = fmaxf(fmaxf(tp, top_cur), prev);
        const float md = fmed3(tp, top_cur, prev);
        const float S  = 1.0f + fast_exp2(mn - md) + fast_exp2(mn - mx);
        const float val = (dv + mn) - fast_log2(S);

        float bn;
        if constexpr (EDGE) {
            const bool valid = (unsigned)(sbase + t - l) < 2048u;
            bn   = valid ? val : INF;
            prev = valid ? val : prev;
        } else {
            bn   = val;
            prev = val;
        }
        if (l == 63) bot[t] = bn;   // LDS (lgkmcnt) — keeps vmcnt clean
        bottom_prev = bn;
        qv = dpp_mov<DPP_WAVE_SHL1>(qv, qv);   // rotate handoff feed
    }
}

// ---------------------------------------------------------------------------
// dp2: 32 blocks x 1 wave. Lane l of block b owns row b*64+l+1 (1-indexed);
// at step s it computes col j = s-l+1. Cross-block handoff via gbuf (LLC,
// relaxed agent atomics) + flag released once per group.
// ---------------------------------------------------------------------------
__global__ __launch_bounds__(64) void dp2(const float4* __restrict__ G4,
                                          int* __restrict__ flags,
                                          float* __restrict__ gbuf,
                                          float* __restrict__ out) {
    __shared__ float bot[KB2];
    const int b = (blockIdx.x % 8) * 4 + blockIdx.x / 8;  // XCD swizzle
    const int l = threadIdx.x;
    const bool store_row = (b != BLK - 1);

    float prev        = INF;
    float top_cur     = (b == 0 && l == 0) ? 0.0f : INF;  // R[0,0] seed
    float bottom_prev = INF;
    float qv          = INF;

    const size_t blk4 = (size_t)b * NGA * 512;  // float4 units per block
    float4 bufA[8], bufB[8];
#pragma unroll
    for (int q = 0; q < 8; ++q) bufA[q] = G4[blk4 + (l << 3) + q];  // group 0

    float* gout = gbuf + (size_t)b * GSTR;
    const float* gin = gbuf + (size_t)(b - 1) * GSTR;
    const int* flagp = flags + (b > 0 ? b - 1 : 0);

    for (int g = 0; g < NGRP2; ++g) {
        if (b > 0 && g < 64) {
            const int need = 32 * g + 32;
            while (__hip_atomic_load(flagp, __ATOMIC_RELAXED,
                                     __HIP_MEMORY_SCOPE_AGENT) < need)
                __builtin_amdgcn_s_sleep(1);
            sched_fence();
            if (l < KB2)
                qv = __hip_atomic_load(&gin[32 * g + l + 1], __ATOMIC_RELAXED,
                                       __HIP_MEMORY_SCOPE_AGENT);
            sched_fence();
        }

        const int   gp  = (g + 1 < NGRP2) ? g + 1 : g;   // clamped prefetch
        const size_t pb4 = blk4 + (size_t)gp * 512 + (l << 3);
        const bool edge  = (g < 2) | (g >= 64);
        const int sbase  = g * KB2;

        if ((g & 1) == 0) {
#pragma unroll
            for (int q = 0; q < 8; ++q) bufB[q] = G4[pb4 + q];
            if (edge) dp_body<true >(sbase, l, prev, top_cur, bottom_prev, qv, bufA, bot);
            else      dp_body<false>(sbase, l, prev, top_cur, bottom_prev, qv, bufA, bot);
        } else {
#pragma unroll
            for (int q = 0; q < 8; ++q) bufA[q] = G4[pb4 + q];
            if (edge) dp_body<true >(sbase, l, prev, top_cur, bottom_prev, qv, bufB, bot);
            else      dp_body<false>(sbase, l, prev, top_cur, bottom_prev, qv, bufB, bot);
        }

        if (store_row) {
            const int c = 32 * g - 62 + l;       // col produced at t=l
            if (l < KB2 && c >= 1 && c <= M)
                __hip_atomic_store(&gout[c], bot[l], __ATOMIC_RELAXED,
                                   __HIP_MEMORY_SCOPE_AGENT);
            if (l == 0) {
                int jd = 32 * g - 31;            // cols <= jd fully published
                if (jd > M) jd = M;
                if (jd > 0)
                    __hip_atomic_store(&flags[b], jd, __ATOMIC_RELEASE,
                                       __HIP_MEMORY_SCOPE_AGENT);
            }
        }
    }

    if (b == BLK - 1 && l == 63) out[0] = prev * LN2;  // R[N, M]
}

// ===========================================================================
// PATH B: single-block pipeline fallback (ws >= 16.8 MB) — unchanged
// ===========================================================================
constexpr int W = 8;
constexpr int T = W * 64;
constexpr int C = N / T;
constexpr int KB = 16;
constexpr int PF = 4;
constexpr int SKW = 63 + KB;
constexpr int S_MAX = (M - 1) + 63 + (W - 1) * SKW;
constexpr int NGROUPS = S_MAX / KB + 1;

__device__ __forceinline__ float softmin_cell(float diag, float up, float left,
                                              float dv) {
    const float m = fminf(fminf(diag, up), left);
    const float s = fast_exp2(m - diag) + fast_exp2(m - up) + fast_exp2(m - left);
    return dv + m - fast_log2(s);
}

__global__ __launch_bounds__(256) void dist_kernel(const float* __restrict__ x,
                                                   const float* __restrict__ y,
                                                   float* __restrict__ Dt) {
    __shared__ float xs[32 * SP];
    __shared__ float ys[32 * SP];
    const int t  = threadIdx.x;
    const int i0 = blockIdx.x * 32;
    const int j0 = blockIdx.y * 32;

    const float4* x4 = (const float4*)(x + (size_t)i0 * K);
    const float4* y4 = (const float4*)(y + (size_t)j0 * K);
#pragma unroll
    for (int idx = t; idx < 512; idx += 256) {
        int row = idx >> 4, c4 = idx & 15;
        *(float4*)&xs[row * SP + c4 * 4] = x4[idx];
        *(float4*)&ys[row * SP + c4 * 4] = y4[idx];
    }
    __syncthreads();

    const int jj = (t >> 4) << 1;
    const int ii = (t & 15) << 1;
    float a00 = 0.f, a01 = 0.f, a10 = 0.f, a11 = 0.f;
#pragma unroll
    for (int k = 0; k < K; k += 2) {
        float2 xa = *(const float2*)&xs[ii * SP + k];
        float2 xb = *(const float2*)&xs[(ii + 1) * SP + k];
        float2 ya = *(const float2*)&ys[jj * SP + k];
        float2 yb = *(const float2*)&ys[(jj + 1) * SP + k];
        float d;
        d = xa.x - ya.x; a00 += d * d;  d = xa.y - ya.y; a00 += d * d;
        d = xb.x - ya.x; a01 += d * d;  d = xb.y - ya.y; a01 += d * d;
        d = xa.x - yb.x; a10 += d * d;  d = xa.y - yb.y; a10 += d * d;
        d = xb.x - yb.x; a11 += d * d;  d = xb.y - yb.y; a11 += d * d;
    }
    float* r0 = Dt + (size_t)(j0 + jj) * N + (i0 + ii);
    float* r1 = Dt + (size_t)(j0 + jj + 1) * N + (i0 + ii);
    *(float2*)r0 = make_float2(a00 * LOG2E, a01 * LOG2E);
    *(float2*)r1 = make_float2(a10 * LOG2E, a11 * LOG2E);
}

__global__ __launch_bounds__(T) void dp_kernel(const float* __restrict__ Dt,
                                               float* __restrict__ out) {
    __shared__ float queue[2][W][KB];
    const int g = threadIdx.x;
    const int w = g >> 6;
    const int l = g & 63;
    const int skew = l + w * SKW;

    for (int i = g; i < 2 * W * KB; i += T) ((float*)queue)[i] = INF;

    float prev[C];
#pragma unroll
    for (int k = 0; k < C; ++k) prev[k] = INF;
    float top_cur     = (g == 0) ? 0.0f : INF;
    float top_prev    = INF;
    float bottom_prev = INF;

    const float4* D4 = (const float4*)Dt;
    float4 ring[PF];
#pragma unroll
    for (int u = 0; u < PF; ++u) {
        int j  = u - skew + 1;
        int jc = min(max(j, 1), M);
        ring[u] = D4[(size_t)(jc - 1) * (N / 4) + g];
    }

    __syncthreads();

    float qv = INF;

    for (int grp = 0; grp < NGROUPS; ++grp) {
        if (w > 0 && l < KB) qv = queue[(grp & 1) ^ 1][w - 1][l];

#pragma unroll
        for (int t = 0; t < KB; ++t) {
            const int j = grp * KB + t - skew + 1;

            float incoming = __shfl_up(bottom_prev, 1);
            const float qq = __shfl(qv, t);
            if (l == 0) incoming = (w == 0) ? INF : qq;
            top_prev = top_cur;
            top_cur  = incoming;

            float bottom_new = INF;
            if (j >= 1 && j <= M) {
                const float4 dq = ring[t & (PF - 1)];
                float diag = top_prev;
                float up   = top_cur;
#pragma unroll
                for (int k = 0; k < C; ++k) {
                    const float left = prev[k];
                    const float dv = (k == 0) ? dq.x : (k == 1) ? dq.y
                                   : (k == 2) ? dq.z : dq.w;
                    const float val = softmin_cell(diag, up, left, dv);
                    diag    = left;
                    up      = val;
                    prev[k] = val;
                }
                bottom_new = up;
            }
            {
                int jc = min(max(j + PF, 1), M);
                ring[t & (PF - 1)] = D4[(size_t)(jc - 1) * (N / 4) + g];
            }

            if (l == 63) queue[grp & 1][w][t] = bottom_new;
            bottom_prev = bottom_new;
        }
        __syncthreads();
    }

    if (g == T - 1) out[0] = prev[C - 1] * LN2;
}

// ===========================================================================
// PATH C: fused fallback (tiny ws)
// ===========================================================================
constexpr int L = N + 1;
__global__ __launch_bounds__(1024) void dp_fused(const float* __restrict__ x,
                                                 const float* __restrict__ y,
                                                 float* __restrict__ out) {
    __shared__ float buf[3][L];
    const int tid = threadIdx.x;
    for (int i = tid; i < L; i += 1024) {
        buf[0][i] = (i == 0) ? 0.0f : INF;
        buf[1][i] = INF;
        buf[2][i] = INF;
    }
    __syncthreads();
    for (int d = 2; d <= N + M; ++d) {
        float* curr = buf[d % 3];
        const float* p1 = buf[(d + 2) % 3];
        const float* p2 = buf[(d + 1) % 3];
        const int ilo = (d - M > 1) ? (d - M) : 1;
        const int ihi = (d - 1 < N) ? (d - 1) : N;
        for (int c = tid; c < ihi - ilo + 1; c += 1024) {
            const int i = ilo + c;
            const float* xr = x + (size_t)(i - 1) * K;
            const float* yr = y + (size_t)(d - i - 1) * K;
            float acc = 0.f;
#pragma unroll
            for (int k = 0; k < K; ++k) { float df = xr[k] - yr[k]; acc += df * df; }
            const float m  = fminf(fminf(p2[i - 1], p1[i - 1]), p1[i]);
            const float ss = __expf(m - p2[i - 1]) + __expf(m - p1[i - 1]) +
                             __expf(m - p1[i]);
            curr[i] = acc + m - __logf(ss);
        }
        if (tid == 0) curr[0] = INF;
        __syncthreads();
    }
    if (tid == 0) out[0] = buf[(N + M) % 3][N];
}

// ===========================================================================
extern "C" void kernel_launch(void* const* d_in, const int* in_sizes, int n_in,
                              void* d_out, int out_size, void* d_ws, size_t ws_size,
                              hipStream_t stream) {
    (void)in_sizes; (void)n_in; (void)out_size;
    const float* x = (const float*)d_in[0];
    const float* y = (const float*)d_in[1];
    float* out = (float*)d_out;

    if (ws_size >= NEED_A) {
        float* Dg    = (float*)d_ws;
        int*   flags = (int*)((char*)d_ws + FLAGS_OFF);
        float* gbuf  = (float*)((char*)d_ws + GBUF_OFF);
        dim3 dg(64, 64);
        dist2<<<dg, 256, 0, stream>>>(x, y, Dg, flags);
        dp2<<<BLK, 64, 0, stream>>>((const float4*)Dg, flags, gbuf, out);
    } else if (ws_size >= (size_t)N * M * sizeof(float)) {
        float* Dt = (float*)d_ws;
        dim3 dg(N / 32, M / 32);
        dist_kernel<<<dg, 256, 0, stream>>>(x, y, Dt);
        dp_kernel<<<1, T, 0, stream>>>(Dt, out);
    } else {
        dp_fused<<<1, 1024, 0, stream>>>(x, y, out);
    }
}